// Round 10
// baseline (167.645 us; speedup 1.0000x reference)
//
#include <hip/hip_runtime.h>
#include <cmath>

// MLDR loss on MI355X, v16: v15 (139.7us, best) + k4 split by coefficient.
//  v15 post-mortem: k4 is latency-bound (VALUBusy 21%, Occ 13%, VGPR 116,
//  1.9 TB/s effective) -- per-thread state for ALL 3 coefs caps occupancy.
//  v16: k4 grid (CHUNKS, 4, 3); each block does ONE coef: 4 y-states,
//  6 table regs, 32 logs/thread. Raw read x3 (192 MB) is L3-served (inputs
//  are L3-resident after k1; v14 FETCH=45MB<64MB proved L3 service).
//   K1: raw -> 16-sample local EMA + inclusive block scan -> B + Eloc.
//   K2: segmented scan -> Y; thread(0,0) zeroes out[0].
//   K3: global long state = Bl + d^(16(tid+1))*Yc -> Etab log2-ratios.
//   K4: per-coef replay from B + Etab lerp; block atomicAdd(out).
//  4 dispatches. B layout = v10 scattered [row][sig][col] (proven).
// Fallback (ws < 30.2 MiB): B buffer reused temporally (long then short).

#define T_LEN    1048576
#define CHUNKS   256
#define CLEN     4096
#define NT1      256
#define SEG1     16       // CLEN / NT1; one B column per thread
#define COLS     65536    // T_LEN / 16
#define JMAX     65535
#define EPS_CLIP 1e-8f
#define K2SEG    32
#define K2NSEG   8

struct K1Args {
  float d[6];
  float apw[6][7];        // (d^16)^(2^i), i=0..6  (i=6 -> d^1024)
};
struct K2Args {
  float dL[6];            // d^4096
  float dL32[6];          // d^(4096*32)
};
struct CarryPack {        // one kind (short or long), 3 coefs
  float d[3];
  float apw[3][9];        // (d^16)^(2^i), i=0..8  (i=8 -> d^4096)
};

__device__ __constant__ const int D_SHIFT[3] = {10804, 31972, 63945};

// ---------------- K1: local EMA + inclusive block scan -> B, Eloc ----------
__global__ __launch_bounds__(NT1)
void k1_stage(const float* __restrict__ xp, const float* __restrict__ xt,
              float* __restrict__ Eloc, float* __restrict__ Bs,
              float* __restrict__ Bl, int mode, K1Args ka)
{
  int chunk = blockIdx.x, b = blockIdx.y;       // b = which*4 + sig
  int which = b >> 2, sig = b & 3, tid = threadIdx.x;
  long base = (long)chunk * CLEN + (long)tid * SEG1;
  const float* x0 = (which ? xt : xp) + (long)sig * 2 * T_LEN;
  const float* x1 = x0 + T_LEN;

  float S[12];                                  // j = cf*2 + st
#pragma unroll
  for (int j = 0; j < 12; j++) S[j] = 0.f;

#pragma unroll
  for (int i = 0; i < SEG1 / 4; i++) {
    float4 a = *(const float4*)(x0 + base + 4*i);
    float4 c4 = *(const float4*)(x1 + base + 4*i);
    float sm, sp, pm, ps;
#define STEP(CMP) \
    sm = a.CMP + c4.CMP; sp = a.CMP - c4.CMP; \
    pm = fmaxf(0.5f * sm * sm, EPS_CLIP); ps = fmaxf(0.5f * sp * sp, EPS_CLIP); \
    _Pragma("unroll") \
    for (int cf = 0; cf < 6; cf++) { \
      S[cf*2+0] = fmaf(ka.d[cf], S[cf*2+0], pm); \
      S[cf*2+1] = fmaf(ka.d[cf], S[cf*2+1], ps); \
    }
    STEP(x) STEP(y) STEP(z) STEP(w)
#undef STEP
  }

  // inclusive chunk-local scan across 256 threads (Hillis-Steele + waves)
  int lane = tid & 63, w = tid >> 6;
#pragma unroll
  for (int i = 0; i < 6; i++) {
#pragma unroll
    for (int j = 0; j < 12; j++) {
      float up = __shfl_up(S[j], 1u << i, 64);
      if (lane >= (1 << i)) S[j] = fmaf(ka.apw[j >> 1][i], up, S[j]);
    }
  }
  __shared__ float WT[4][12];
  if (lane == 63)
#pragma unroll
    for (int j = 0; j < 12; j++) WT[w][j] = S[j];
  __syncthreads();
  float C[12];
#pragma unroll
  for (int j = 0; j < 12; j++) C[j] = 0.f;
#pragma unroll
  for (int i = 0; i < 4; i++) {
    if (i < w) {
#pragma unroll
      for (int j = 0; j < 12; j++)
        C[j] = fmaf(ka.apw[j >> 1][6], C[j], WT[i][j]);   // A = d^1024
    }
  }
  float alp[6];                                 // a16^(lane+1)
#pragma unroll
  for (int cf = 0; cf < 6; cf++) {
    int e = lane + 1;
    float a = 1.f;
#pragma unroll
    for (int i = 0; i < 7; i++)
      if (e & (1 << i)) a *= ka.apw[cf][i];
    alp[cf] = a;
  }
#pragma unroll
  for (int j = 0; j < 12; j++) S[j] = fmaf(alp[j >> 1], C[j], S[j]);

  long col = (long)chunk * (CLEN / SEG1) + tid;
  if (mode & 2) {                               // short rows: r = 4k+which*2+st
#pragma unroll
    for (int k = 0; k < 3; k++)
#pragma unroll
      for (int st2 = 0; st2 < 2; st2++)
        Bs[(long)(4*k + which*2 + st2) * (4L*COLS) + (long)sig*COLS + col] = S[4*k + st2];
  }
  if (mode & 1) {                               // long rows
#pragma unroll
    for (int k = 0; k < 3; k++)
#pragma unroll
      for (int st2 = 0; st2 < 2; st2++)
        Bl[(long)(4*k + which*2 + st2) * (4L*COLS) + (long)sig*COLS + col] = S[4*k + 2 + st2];
  }
  if (mode != 2 && tid == NT1 - 1) {            // chunk-end state -> Eloc
#pragma unroll
    for (int cf = 0; cf < 6; cf++)
#pragma unroll
      for (int st = 0; st < 2; st++)
        Eloc[chunk * 96 + (which*8 + sig*2 + st) * 6 + cf] = S[cf*2 + st];
  }
}

// ---------------- K2: segmented scan (96 cols x 8 segments); zero out ------
__global__ __launch_bounds__(768)
void k2_scan(const float* __restrict__ Eloc, float* __restrict__ Y, K2Args ka,
             float* __restrict__ out)
{
  int col = threadIdx.x;        // 0..95
  int seg = threadIdx.y;        // 0..7
  if (col == 0 && seg == 0) out[0] = 0.f;       // zero for k4's atomics
  float dL = ka.dL[col % 6];
  float A  = ka.dL32[col % 6];
  int c0 = seg * K2SEG;

  float yloc[K2SEG];
  float y = 0.f;
#pragma unroll
  for (int i = 0; i < K2SEG; i++) {
    y = fmaf(dL, y, Eloc[(c0 + i) * 96 + col]);
    yloc[i] = y;
  }
  __shared__ float SY[K2NSEG][96];
  SY[seg][col] = y;
  __syncthreads();
  float C = 0.f;
  for (int s = 0; s < seg; s++) C = fmaf(A, C, SY[s][col]);
  float w = dL;
#pragma unroll
  for (int i = 0; i < K2SEG; i++) {
    Y[(c0 + i) * 96 + col] = fmaf(w, C, yloc[i]);
    w *= dL;
  }
}

// ---------------- K3: long table from B (no scan, no raw read) -------------
__global__ __launch_bounds__(256)
void k3_table(const float* __restrict__ Bl, const float* __restrict__ Y,
              float* __restrict__ Etab, CarryPack cp)
{
  int chunk = blockIdx.x, sig = blockIdx.y, tid = threadIdx.x;
  long col = (long)chunk * 256 + tid;

  float Yc[12];
#pragma unroll
  for (int j = 0; j < 12; j++) Yc[j] = 0.f;
  if (chunk > 0) {
    const float* Yp = Y + (chunk - 1) * 96;
    int rm = sig * 2;
#pragma unroll
    for (int k = 0; k < 3; k++) {
      int cf = 2*k + 1;
      Yc[4*k+0] = Yp[rm*6 + cf];       Yc[4*k+1] = Yp[(rm+1)*6 + cf];
      Yc[4*k+2] = Yp[(8+rm)*6 + cf];   Yc[4*k+3] = Yp[(8+rm+1)*6 + cf];
    }
  }
  float fac[3];                                 // a16^(tid+1), tid+1 in [1,256]
#pragma unroll
  for (int k = 0; k < 3; k++) {
    int e = tid + 1;
    float a = 1.f;
#pragma unroll
    for (int i = 0; i < 9; i++)
      if (e & (1 << i)) a *= cp.apw[k][i];
    fac[k] = a;
  }
#pragma unroll
  for (int k = 0; k < 3; k++) {
    float y0 = fmaf(fac[k], Yc[4*k+0], Bl[(long)(4*k+0)*(4L*COLS) + (long)sig*COLS + col]);
    float y1 = fmaf(fac[k], Yc[4*k+1], Bl[(long)(4*k+1)*(4L*COLS) + (long)sig*COLS + col]);
    float y2 = fmaf(fac[k], Yc[4*k+2], Bl[(long)(4*k+2)*(4L*COLS) + (long)sig*COLS + col]);
    float y3 = fmaf(fac[k], Yc[4*k+3], Bl[(long)(4*k+3)*(4L*COLS) + (long)sig*COLS + col]);
    float em = __log2f(y0) - __log2f(y2);       // log2-ratio table
    float es = __log2f(y1) - __log2f(y3);
    long rowm = (long)(k*8 + sig*2);
    Etab[rowm * COLS + col] = em;
    Etab[(rowm+1) * COLS + col] = es;
  }
}

// slow-path lerp with warmup/end clamps (rare threads only)
__device__ __forceinline__ float slow_lerp(const float* __restrict__ row, int q)
{
  int qm = q - 15;
  if (qm < 0) return row[0];
  int j = qm >> 4;
  if (j >= JMAX) return row[JMAX];
  float f = (float)(qm & 15) * 0.0625f;
  float a = row[j], b = row[j + 1];
  return fmaf(f, b - a, a);
}

// ---------------- K4: per-coef replay from B + table lerp + atomic ---------
__global__ __launch_bounds__(256)
void k4all(const float* __restrict__ xp, const float* __restrict__ xt,
           const float* __restrict__ Y, const float* __restrict__ Bs,
           const float* __restrict__ Etab, CarryPack cp, float* __restrict__ out)
{
  int chunk = blockIdx.x, sig = blockIdx.y, ks = blockIdx.z, tid = threadIdx.x;
  long col = (long)chunk * 256 + tid;
  long base = col * 16;

  // carry-in: global short-EMA states (this coef only) at sample base-1
  float Yc0 = 0.f, Yc1 = 0.f, Yc2 = 0.f, Yc3 = 0.f;
  if (chunk > 0) {
    const float* Yp = Y + (chunk - 1) * 96;
    int rm = sig * 2, cf = 2 * ks;
    Yc0 = Yp[rm*6 + cf];       Yc1 = Yp[(rm+1)*6 + cf];
    Yc2 = Yp[(8+rm)*6 + cf];   Yc3 = Yp[(8+rm+1)*6 + cf];
  }
  float y0, y1, y2, y3;
  if (tid == 0) {
    y0 = Yc0; y1 = Yc1; y2 = Yc2; y3 = Yc3;     // Y[chunk-1] is exact carry
  } else {
    float a = 1.f;                              // a16^tid, tid in [1,256)
#pragma unroll
    for (int i = 0; i < 8; i++)
      if (tid & (1 << i)) a *= cp.apw[ks][i];
    long pc = (long)sig * COLS + (col - 1);
    y0 = fmaf(a, Yc0, Bs[(long)(4*ks+0)*(4L*COLS) + pc]);
    y1 = fmaf(a, Yc1, Bs[(long)(4*ks+1)*(4L*COLS) + pc]);
    y2 = fmaf(a, Yc2, Bs[(long)(4*ks+2)*(4L*COLS) + pc]);
    y3 = fmaf(a, Yc3, Bs[(long)(4*ks+3)*(4L*COLS) + pc]);
  }

  // table fetches (issued early; L2-resident)
  const float* Tm = Etab + (long)(ks * 8 + sig * 2) * COLS;
  const float* Ts = Tm + COLS;
  int q0 = (int)base + D_SHIFT[ks]; if (q0 >= T_LEN) q0 -= T_LEN;
  int qm0 = q0 - 15;
  bool fastp = (qm0 >= 0) && ((qm0 >> 4) <= JMAX - 2);
  int j0 = fastp ? (qm0 >> 4) : 0;
  int ofs = fastp ? (qm0 & 15) : 0;
  float tm0 = Tm[j0], tm1 = Tm[j0 + 1], tm2 = Tm[j0 + 2];
  float ts0 = Ts[j0], ts1 = Ts[j0 + 1], ts2 = Ts[j0 + 2];

  const float* p0 = xp + (long)sig * 2 * T_LEN;
  const float* p1 = p0 + T_LEN;
  const float* t0 = xt + (long)sig * 2 * T_LEN;
  const float* t1 = t0 + T_LEN;
  float dd = cp.d[ks];

  float acc0 = 0.f, acc1 = 0.f;
#pragma unroll
  for (int qt = 0; qt < 4; qt++) {
    float4 a4 = *(const float4*)(p0 + base + 4*qt);
    float4 b4 = *(const float4*)(p1 + base + 4*qt);
    float4 u4 = *(const float4*)(t0 + base + 4*qt);
    float4 w4 = *(const float4*)(t1 + base + 4*qt);
#define SAMP(CI, CMP) { \
      const int m = 4*qt + CI; \
      float sm = a4.CMP + b4.CMP, sd = a4.CMP - b4.CMP; \
      float pm = fmaxf(0.5f*sm*sm, EPS_CLIP), ps = fmaxf(0.5f*sd*sd, EPS_CLIP); \
      float em_ = u4.CMP + w4.CMP, ed_ = u4.CMP - w4.CMP; \
      float qm_ = fmaxf(0.5f*em_*em_, EPS_CLIP), qs_ = fmaxf(0.5f*ed_*ed_, EPS_CLIP); \
      y0 = fmaf(dd, y0, pm);  y1 = fmaf(dd, y1, ps); \
      y2 = fmaf(dd, y2, qm_); y3 = fmaf(dd, y3, qs_); \
      float Dm = __log2f(y0) - __log2f(y2); \
      float Ds = __log2f(y1) - __log2f(y3); \
      float em, es; \
      if (fastp) { \
        int d0 = ofs + m; \
        bool hi = d0 >= 16; \
        float am = hi ? tm1 : tm0, bm = hi ? tm2 : tm1; \
        float as = hi ? ts1 : ts0, bs = hi ? ts2 : ts1; \
        float f = (float)(d0 - (hi ? 16 : 0)) * 0.0625f; \
        em = fmaf(f, bm - am, am); \
        es = fmaf(f, bs - as, as); \
      } else { \
        int q = q0 + m; if (q >= T_LEN) q -= T_LEN; \
        em = slow_lerp(Tm, q); \
        es = slow_lerp(Ts, q); \
      } \
      acc0 += fabsf(Dm - em); \
      acc1 += fabsf(Ds - es); \
    }
    SAMP(0,x) SAMP(1,y) SAMP(2,z) SAMP(3,w)
#undef SAMP
  }

  float acc = acc0 + acc1;
#pragma unroll
  for (int off = 32; off > 0; off >>= 1) acc += __shfl_down(acc, off, 64);
  __shared__ float psum[4];
  int lane = tid & 63, w = tid >> 6;
  if (lane == 0) psum[w] = acc;
  __syncthreads();
  if (tid == 0) {
    const float SCALE = (float)(0.6931471805599453 / (8.0 * 1048576.0));
    float s = psum[0] + psum[1] + psum[2] + psum[3];
    atomicAdd(out, s * SCALE);                  // device-scope; absorbs k5
  }
}

extern "C" void kernel_launch(void* const* d_in, const int* in_sizes, int n_in,
                              void* d_out, int out_size, void* d_ws, size_t ws_size,
                              hipStream_t stream)
{
  (void)in_sizes; (void)n_in; (void)out_size;
  const float* xp = (const float*)d_in[0];
  const float* xt = (const float*)d_in[1];
  float* out = (float*)d_out;
  char* ws = (char*)d_ws;

  const size_t OFF_ELOC = 0;          // 256*96*4 = 98304
  const size_t OFF_Y    = 98304;      // 98304
  const size_t OFF_ETAB = 212992;     // 24*65536*4 = 6 MB, ends 6504448
  const size_t OFF_B    = 6504448;    // 12 rows = 12.6 MB; 24 rows = 25.2 MB
  const size_t HALF_B   = 12L * 4 * COLS * 4;          // 12582912
  const size_t NEED_FULL = OFF_B + 2 * HALF_B;         // 31670272 (~30.2 MiB)
  float* Eloc = (float*)(ws + OFF_ELOC);
  float* Ybuf = (float*)(ws + OFF_Y);
  float* Etab = (float*)(ws + OFF_ETAB);
  float* Bsh  = (float*)(ws + OFF_B);                  // short rows
  float* Blo  = (float*)(ws + OFF_B + HALF_B);         // long rows (full mode)

  static const double S_MS[3] = {10.0, 50.0, 100.0};
  static const double L_MS[3] = {500.0, 1500.0, 3000.0};

  K1Args k1a; K2Args k2a; CarryPack cpS, cpL;
  for (int k = 0; k < 3; k++) {
    for (int which = 0; which < 2; which++) {
      int idx = 2 * k + which;
      double ms = which ? L_MS[k] : S_MS[k];
      float cF = (float)(1.0 - std::exp(-2200.0 / (ms * 44100.0)));
      float dF = 1.0f - cF;               // exact fp32 match to reference
      k1a.d[idx] = dF;
      double a16 = std::pow((double)dF, 16.0);
      for (int i = 0; i < 7; i++)
        k1a.apw[idx][i] = (float)std::pow(a16, (double)(1 << i));
      k2a.dL[idx]   = (float)std::pow((double)dF, (double)CLEN);
      k2a.dL32[idx] = (float)std::pow((double)dF, (double)CLEN * (double)K2SEG);
      CarryPack& cp = which ? cpL : cpS;
      cp.d[k] = dF;
      for (int i = 0; i < 9; i++)
        cp.apw[k][i] = (float)std::pow(a16, (double)(1 << i));
    }
  }

  bool full = (ws_size >= NEED_FULL);
  if (full) {
    k1_stage<<<dim3(CHUNKS, 8), NT1, 0, stream>>>(xp, xt, Eloc, Bsh, Blo, 3, k1a);
    k2_scan<<<dim3(1), dim3(96, K2NSEG), 0, stream>>>(Eloc, Ybuf, k2a, out);
    k3_table<<<dim3(CHUNKS, 4), 256, 0, stream>>>(Blo, Ybuf, Etab, cpL);
    k4all<<<dim3(CHUNKS, 4, 3), 256, 0, stream>>>(xp, xt, Ybuf, Bsh, Etab, cpS, out);
  } else {
    // 19.1 MB budget: reuse the single 12-row B buffer temporally
    k1_stage<<<dim3(CHUNKS, 8), NT1, 0, stream>>>(xp, xt, Eloc, Bsh, Bsh, 1, k1a);
    k2_scan<<<dim3(1), dim3(96, K2NSEG), 0, stream>>>(Eloc, Ybuf, k2a, out);
    k3_table<<<dim3(CHUNKS, 4), 256, 0, stream>>>(Bsh, Ybuf, Etab, cpL);
    k1_stage<<<dim3(CHUNKS, 8), NT1, 0, stream>>>(xp, xt, Eloc, Bsh, Bsh, 2, k1a);
    k4all<<<dim3(CHUNKS, 4, 3), 256, 0, stream>>>(xp, xt, Ybuf, Bsh, Etab, cpS, out);
  }
}

// Round 11
// 146.952 us; speedup vs baseline: 1.1408x; 1.1408x over previous
//
#include <hip/hip_runtime.h>
#include <cmath>

// MLDR loss on MI355X, v17: v15 (139.7us, best) + k4 split by STREAM ROLE.
//  v16 post-mortem: coef-split tripled raw reads (3 blocks/chunk on
//  different XCDs -> no L2 share) -> k4 60us. v17 splits WITHOUT read
//  duplication: NT4=512; thread pair (2c,2c+1) = (pred-role, true-role) of
//  column c. Each thread: 2 raw streams (total unchanged), 6 EMA states,
//  3 table regs (m-row vs s-row of Etab), 2 logs/sample-coef; one
//  __shfl_xor(.,1) swaps the cross terms (Dm=l0-l2 on role0, Ds=l1-l3 on
//  role1). Waves 4096->8192 (32/CU), per-thread VGPR ~halved.
//   K1: raw -> 16-sample local EMA + inclusive block scan -> B + Eloc.
//   K2: segmented scan -> Y; thread(0,0) zeroes out[0].
//   K3: global long state = Bl + d^(16(tid+1))*Yc -> Etab log2-ratios.
//   K4: per-role replay from B + Etab lerp; block atomicAdd(out).
//  4 dispatches. B layout = v10 scattered [row][sig][col] (proven).
// Fallback (ws < 30.2 MiB): B buffer reused temporally (long then short).

#define T_LEN    1048576
#define CHUNKS   256
#define CLEN     4096
#define NT1      256
#define SEG1     16       // CLEN / NT1; one B column per thread
#define COLS     65536    // T_LEN / 16
#define JMAX     65535
#define EPS_CLIP 1e-8f
#define K2SEG    32
#define K2NSEG   8

struct K1Args {
  float d[6];
  float apw[6][7];        // (d^16)^(2^i), i=0..6  (i=6 -> d^1024)
};
struct K2Args {
  float dL[6];            // d^4096
  float dL32[6];          // d^(4096*32)
};
struct CarryPack {        // one kind (short or long), 3 coefs
  float d[3];
  float apw[3][9];        // (d^16)^(2^i), i=0..8  (i=8 -> d^4096)
};

__device__ __constant__ const int D_SHIFT[3] = {10804, 31972, 63945};

// ---------------- K1: local EMA + inclusive block scan -> B, Eloc ----------
__global__ __launch_bounds__(NT1)
void k1_stage(const float* __restrict__ xp, const float* __restrict__ xt,
              float* __restrict__ Eloc, float* __restrict__ Bs,
              float* __restrict__ Bl, int mode, K1Args ka)
{
  int chunk = blockIdx.x, b = blockIdx.y;       // b = which*4 + sig
  int which = b >> 2, sig = b & 3, tid = threadIdx.x;
  long base = (long)chunk * CLEN + (long)tid * SEG1;
  const float* x0 = (which ? xt : xp) + (long)sig * 2 * T_LEN;
  const float* x1 = x0 + T_LEN;

  float S[12];                                  // j = cf*2 + st
#pragma unroll
  for (int j = 0; j < 12; j++) S[j] = 0.f;

#pragma unroll
  for (int i = 0; i < SEG1 / 4; i++) {
    float4 a = *(const float4*)(x0 + base + 4*i);
    float4 c4 = *(const float4*)(x1 + base + 4*i);
    float sm, sp, pm, ps;
#define STEP(CMP) \
    sm = a.CMP + c4.CMP; sp = a.CMP - c4.CMP; \
    pm = fmaxf(0.5f * sm * sm, EPS_CLIP); ps = fmaxf(0.5f * sp * sp, EPS_CLIP); \
    _Pragma("unroll") \
    for (int cf = 0; cf < 6; cf++) { \
      S[cf*2+0] = fmaf(ka.d[cf], S[cf*2+0], pm); \
      S[cf*2+1] = fmaf(ka.d[cf], S[cf*2+1], ps); \
    }
    STEP(x) STEP(y) STEP(z) STEP(w)
#undef STEP
  }

  // inclusive chunk-local scan across 256 threads (Hillis-Steele + waves)
  int lane = tid & 63, w = tid >> 6;
#pragma unroll
  for (int i = 0; i < 6; i++) {
#pragma unroll
    for (int j = 0; j < 12; j++) {
      float up = __shfl_up(S[j], 1u << i, 64);
      if (lane >= (1 << i)) S[j] = fmaf(ka.apw[j >> 1][i], up, S[j]);
    }
  }
  __shared__ float WT[4][12];
  if (lane == 63)
#pragma unroll
    for (int j = 0; j < 12; j++) WT[w][j] = S[j];
  __syncthreads();
  float C[12];
#pragma unroll
  for (int j = 0; j < 12; j++) C[j] = 0.f;
#pragma unroll
  for (int i = 0; i < 4; i++) {
    if (i < w) {
#pragma unroll
      for (int j = 0; j < 12; j++)
        C[j] = fmaf(ka.apw[j >> 1][6], C[j], WT[i][j]);   // A = d^1024
    }
  }
  float alp[6];                                 // a16^(lane+1)
#pragma unroll
  for (int cf = 0; cf < 6; cf++) {
    int e = lane + 1;
    float a = 1.f;
#pragma unroll
    for (int i = 0; i < 7; i++)
      if (e & (1 << i)) a *= ka.apw[cf][i];
    alp[cf] = a;
  }
#pragma unroll
  for (int j = 0; j < 12; j++) S[j] = fmaf(alp[j >> 1], C[j], S[j]);

  long col = (long)chunk * (CLEN / SEG1) + tid;
  if (mode & 2) {                               // short rows: r = 4k+which*2+st
#pragma unroll
    for (int k = 0; k < 3; k++)
#pragma unroll
      for (int st2 = 0; st2 < 2; st2++)
        Bs[(long)(4*k + which*2 + st2) * (4L*COLS) + (long)sig*COLS + col] = S[4*k + st2];
  }
  if (mode & 1) {                               // long rows
#pragma unroll
    for (int k = 0; k < 3; k++)
#pragma unroll
      for (int st2 = 0; st2 < 2; st2++)
        Bl[(long)(4*k + which*2 + st2) * (4L*COLS) + (long)sig*COLS + col] = S[4*k + 2 + st2];
  }
  if (mode != 2 && tid == NT1 - 1) {            // chunk-end state -> Eloc
#pragma unroll
    for (int cf = 0; cf < 6; cf++)
#pragma unroll
      for (int st = 0; st < 2; st++)
        Eloc[chunk * 96 + (which*8 + sig*2 + st) * 6 + cf] = S[cf*2 + st];
  }
}

// ---------------- K2: segmented scan (96 cols x 8 segments); zero out ------
__global__ __launch_bounds__(768)
void k2_scan(const float* __restrict__ Eloc, float* __restrict__ Y, K2Args ka,
             float* __restrict__ out)
{
  int col = threadIdx.x;        // 0..95
  int seg = threadIdx.y;        // 0..7
  if (col == 0 && seg == 0) out[0] = 0.f;       // zero for k4's atomics
  float dL = ka.dL[col % 6];
  float A  = ka.dL32[col % 6];
  int c0 = seg * K2SEG;

  float yloc[K2SEG];
  float y = 0.f;
#pragma unroll
  for (int i = 0; i < K2SEG; i++) {
    y = fmaf(dL, y, Eloc[(c0 + i) * 96 + col]);
    yloc[i] = y;
  }
  __shared__ float SY[K2NSEG][96];
  SY[seg][col] = y;
  __syncthreads();
  float C = 0.f;
  for (int s = 0; s < seg; s++) C = fmaf(A, C, SY[s][col]);
  float w = dL;
#pragma unroll
  for (int i = 0; i < K2SEG; i++) {
    Y[(c0 + i) * 96 + col] = fmaf(w, C, yloc[i]);
    w *= dL;
  }
}

// ---------------- K3: long table from B (no scan, no raw read) -------------
__global__ __launch_bounds__(256)
void k3_table(const float* __restrict__ Bl, const float* __restrict__ Y,
              float* __restrict__ Etab, CarryPack cp)
{
  int chunk = blockIdx.x, sig = blockIdx.y, tid = threadIdx.x;
  long col = (long)chunk * 256 + tid;

  float Yc[12];
#pragma unroll
  for (int j = 0; j < 12; j++) Yc[j] = 0.f;
  if (chunk > 0) {
    const float* Yp = Y + (chunk - 1) * 96;
    int rm = sig * 2;
#pragma unroll
    for (int k = 0; k < 3; k++) {
      int cf = 2*k + 1;
      Yc[4*k+0] = Yp[rm*6 + cf];       Yc[4*k+1] = Yp[(rm+1)*6 + cf];
      Yc[4*k+2] = Yp[(8+rm)*6 + cf];   Yc[4*k+3] = Yp[(8+rm+1)*6 + cf];
    }
  }
  float fac[3];                                 // a16^(tid+1), tid+1 in [1,256]
#pragma unroll
  for (int k = 0; k < 3; k++) {
    int e = tid + 1;
    float a = 1.f;
#pragma unroll
    for (int i = 0; i < 9; i++)
      if (e & (1 << i)) a *= cp.apw[k][i];
    fac[k] = a;
  }
#pragma unroll
  for (int k = 0; k < 3; k++) {
    float y0 = fmaf(fac[k], Yc[4*k+0], Bl[(long)(4*k+0)*(4L*COLS) + (long)sig*COLS + col]);
    float y1 = fmaf(fac[k], Yc[4*k+1], Bl[(long)(4*k+1)*(4L*COLS) + (long)sig*COLS + col]);
    float y2 = fmaf(fac[k], Yc[4*k+2], Bl[(long)(4*k+2)*(4L*COLS) + (long)sig*COLS + col]);
    float y3 = fmaf(fac[k], Yc[4*k+3], Bl[(long)(4*k+3)*(4L*COLS) + (long)sig*COLS + col]);
    float em = __log2f(y0) - __log2f(y2);       // log2-ratio table
    float es = __log2f(y1) - __log2f(y3);
    long rowm = (long)(k*8 + sig*2);
    Etab[rowm * COLS + col] = em;
    Etab[(rowm+1) * COLS + col] = es;
  }
}

// slow-path lerp with warmup/end clamps (rare threads only)
__device__ __forceinline__ float slow_lerp(const float* __restrict__ row, int q)
{
  int qm = q - 15;
  if (qm < 0) return row[0];
  int j = qm >> 4;
  if (j >= JMAX) return row[JMAX];
  float f = (float)(qm & 15) * 0.0625f;
  float a = row[j], b = row[j + 1];
  return fmaf(f, b - a, a);
}

// ---------------- K4: role-split replay from B + table lerp + atomic -------
// tid pair (2c, 2c+1): role 0 = pred streams (y0,y1), role 1 = true (y2,y3).
// Dm = l0-l2 on role0, Ds = l1-l3 on role1; one shfl_xor(.,1) per
// (sample,coef) exchanges the cross logs. Raw/B/Y/Etab reads are SPLIT,
// never duplicated.
__global__ __launch_bounds__(512)
void k4all(const float* __restrict__ xp, const float* __restrict__ xt,
           const float* __restrict__ Y, const float* __restrict__ Bs,
           const float* __restrict__ Etab, CarryPack cp, float* __restrict__ out)
{
  int chunk = blockIdx.x, sig = blockIdx.y, tid = threadIdx.x;
  int cl = tid >> 1, role = tid & 1;
  long col = (long)chunk * 256 + cl;
  long base = col * 16;

  // carry-in: 6 global short-EMA states (this role's 2 streams x 3 coefs)
  float Yc[6];
#pragma unroll
  for (int j = 0; j < 6; j++) Yc[j] = 0.f;
  if (chunk > 0) {
    const float* Yp = Y + (chunk - 1) * 96;
    int rm = sig * 2 + (role ? 8 : 0);
#pragma unroll
    for (int k = 0; k < 3; k++) {
      int cf = 2*k;
      Yc[2*k+0] = Yp[rm*6 + cf];
      Yc[2*k+1] = Yp[(rm+1)*6 + cf];
    }
  }
  float y[6];
  if (cl == 0) {
#pragma unroll
    for (int j = 0; j < 6; j++) y[j] = Yc[j];   // Y[chunk-1] is exact carry
  } else {
    float fac[3];                               // a16^cl, cl in [1,256)
#pragma unroll
    for (int k = 0; k < 3; k++) {
      float a = 1.f;
#pragma unroll
      for (int i = 0; i < 8; i++)
        if (cl & (1 << i)) a *= cp.apw[k][i];
      fac[k] = a;
    }
    long pc = (long)sig * COLS + (col - 1);
#pragma unroll
    for (int k = 0; k < 3; k++) {
      y[2*k+0] = fmaf(fac[k], Yc[2*k+0], Bs[(long)(4*k + 2*role + 0)*(4L*COLS) + pc]);
      y[2*k+1] = fmaf(fac[k], Yc[2*k+1], Bs[(long)(4*k + 2*role + 1)*(4L*COLS) + pc]);
    }
  }

  // table fetches (this role's row only; issued early; L2-resident)
  const float* Trow[3];
  float t0[3], t1[3], t2[3];
  int ofs[3], q0a[3]; bool fastp[3];
#pragma unroll
  for (int k = 0; k < 3; k++) {
    int q0 = (int)base + D_SHIFT[k]; if (q0 >= T_LEN) q0 -= T_LEN;
    q0a[k] = q0;
    int qm0 = q0 - 15;
    bool f = (qm0 >= 0) && ((qm0 >> 4) <= JMAX - 2);
    fastp[k] = f;
    Trow[k] = Etab + (long)(k * 8 + sig * 2 + role) * COLS;
    int j0 = f ? (qm0 >> 4) : 0;
    ofs[k] = f ? (qm0 & 15) : 0;
    t0[k] = Trow[k][j0]; t1[k] = Trow[k][j0 + 1]; t2[k] = Trow[k][j0 + 2];
  }

  // raw: this role's 2 streams only (pred mid/side or true mid/side)
  const float* xA = (role ? xt : xp) + (long)sig * 2 * T_LEN;
  const float* xB = xA + T_LEN;

  float acc = 0.f;
#pragma unroll
  for (int qt = 0; qt < 4; qt++) {
    float4 a4 = *(const float4*)(xA + base + 4*qt);
    float4 b4 = *(const float4*)(xB + base + 4*qt);
#define SAMP(CI, CMP) { \
      const int m = 4*qt + CI; \
      float s1 = a4.CMP + b4.CMP, s2 = a4.CMP - b4.CMP; \
      float p0 = fmaxf(0.5f*s1*s1, EPS_CLIP), p1 = fmaxf(0.5f*s2*s2, EPS_CLIP); \
      _Pragma("unroll") \
      for (int k = 0; k < 3; k++) { \
        float dd = cp.d[k]; \
        y[2*k+0] = fmaf(dd, y[2*k+0], p0); \
        y[2*k+1] = fmaf(dd, y[2*k+1], p1); \
        float lg0 = __log2f(y[2*k+0]); \
        float lg1 = __log2f(y[2*k+1]); \
        float send = role ? lg0 : lg1; \
        float recv = __shfl_xor(send, 1, 64); \
        float diff = role ? (recv - lg1) : (lg0 - recv); \
        float Ev; \
        if (fastp[k]) { \
          int d0 = ofs[k] + m; \
          bool hi = d0 >= 16; \
          float fa = hi ? t1[k] : t0[k], fb = hi ? t2[k] : t1[k]; \
          float f = (float)(d0 - (hi ? 16 : 0)) * 0.0625f; \
          Ev = fmaf(f, fb - fa, fa); \
        } else { \
          int q = q0a[k] + m; if (q >= T_LEN) q -= T_LEN; \
          Ev = slow_lerp(Trow[k], q); \
        } \
        acc += fabsf(diff - Ev); \
      } \
    }
    SAMP(0,x) SAMP(1,y) SAMP(2,z) SAMP(3,w)
#undef SAMP
  }

#pragma unroll
  for (int off = 32; off > 0; off >>= 1) acc += __shfl_down(acc, off, 64);
  __shared__ float psum[8];
  int lane = tid & 63, w = tid >> 6;
  if (lane == 0) psum[w] = acc;
  __syncthreads();
  if (tid == 0) {
    const float SCALE = (float)(0.6931471805599453 / (8.0 * 1048576.0));
    float s = 0.f;
#pragma unroll
    for (int i = 0; i < 8; i++) s += psum[i];
    atomicAdd(out, s * SCALE);                  // device-scope; absorbs k5
  }
}

extern "C" void kernel_launch(void* const* d_in, const int* in_sizes, int n_in,
                              void* d_out, int out_size, void* d_ws, size_t ws_size,
                              hipStream_t stream)
{
  (void)in_sizes; (void)n_in; (void)out_size;
  const float* xp = (const float*)d_in[0];
  const float* xt = (const float*)d_in[1];
  float* out = (float*)d_out;
  char* ws = (char*)d_ws;

  const size_t OFF_ELOC = 0;          // 256*96*4 = 98304
  const size_t OFF_Y    = 98304;      // 98304
  const size_t OFF_ETAB = 212992;     // 24*65536*4 = 6 MB, ends 6504448
  const size_t OFF_B    = 6504448;    // 12 rows = 12.6 MB; 24 rows = 25.2 MB
  const size_t HALF_B   = 12L * 4 * COLS * 4;          // 12582912
  const size_t NEED_FULL = OFF_B + 2 * HALF_B;         // 31670272 (~30.2 MiB)
  float* Eloc = (float*)(ws + OFF_ELOC);
  float* Ybuf = (float*)(ws + OFF_Y);
  float* Etab = (float*)(ws + OFF_ETAB);
  float* Bsh  = (float*)(ws + OFF_B);                  // short rows
  float* Blo  = (float*)(ws + OFF_B + HALF_B);         // long rows (full mode)

  static const double S_MS[3] = {10.0, 50.0, 100.0};
  static const double L_MS[3] = {500.0, 1500.0, 3000.0};

  K1Args k1a; K2Args k2a; CarryPack cpS, cpL;
  for (int k = 0; k < 3; k++) {
    for (int which = 0; which < 2; which++) {
      int idx = 2 * k + which;
      double ms = which ? L_MS[k] : S_MS[k];
      float cF = (float)(1.0 - std::exp(-2200.0 / (ms * 44100.0)));
      float dF = 1.0f - cF;               // exact fp32 match to reference
      k1a.d[idx] = dF;
      double a16 = std::pow((double)dF, 16.0);
      for (int i = 0; i < 7; i++)
        k1a.apw[idx][i] = (float)std::pow(a16, (double)(1 << i));
      k2a.dL[idx]   = (float)std::pow((double)dF, (double)CLEN);
      k2a.dL32[idx] = (float)std::pow((double)dF, (double)CLEN * (double)K2SEG);
      CarryPack& cp = which ? cpL : cpS;
      cp.d[k] = dF;
      for (int i = 0; i < 9; i++)
        cp.apw[k][i] = (float)std::pow(a16, (double)(1 << i));
    }
  }

  bool full = (ws_size >= NEED_FULL);
  if (full) {
    k1_stage<<<dim3(CHUNKS, 8), NT1, 0, stream>>>(xp, xt, Eloc, Bsh, Blo, 3, k1a);
    k2_scan<<<dim3(1), dim3(96, K2NSEG), 0, stream>>>(Eloc, Ybuf, k2a, out);
    k3_table<<<dim3(CHUNKS, 4), 256, 0, stream>>>(Blo, Ybuf, Etab, cpL);
    k4all<<<dim3(CHUNKS, 4), 512, 0, stream>>>(xp, xt, Ybuf, Bsh, Etab, cpS, out);
  } else {
    // 19.1 MB budget: reuse the single 12-row B buffer temporally
    k1_stage<<<dim3(CHUNKS, 8), NT1, 0, stream>>>(xp, xt, Eloc, Bsh, Bsh, 1, k1a);
    k2_scan<<<dim3(1), dim3(96, K2NSEG), 0, stream>>>(Eloc, Ybuf, k2a, out);
    k3_table<<<dim3(CHUNKS, 4), 256, 0, stream>>>(Bsh, Ybuf, Etab, cpL);
    k1_stage<<<dim3(CHUNKS, 8), NT1, 0, stream>>>(xp, xt, Eloc, Bsh, Bsh, 2, k1a);
    k4all<<<dim3(CHUNKS, 4), 512, 0, stream>>>(xp, xt, Ybuf, Bsh, Etab, cpS, out);
  }
}

// Round 13
// 136.327 us; speedup vs baseline: 1.2297x; 1.0779x over previous
//
#include <hip/hip_runtime.h>
#include <cmath>

// MLDR loss on MI355X, v18 (resubmit -- round 12 bench was an infra failure,
// kernel never measured): v15 (139.7us, best) + k4 slow-path elimination.
//  v16/v17 post-mortems: k4 splits (coef / role) both regressed -- read
//  duplication (v16) or unchanged VGPR + shfl overhead (v17). k4 is
//  L3-latency-bound at 4 waves/SIMD (VGPR ~116). v18 keeps v15's k4 shape
//  and removes the dual fast/slow table path: ONE clamped lerp
//  (qc = clamp(q0-15, 0, (JMAX-2)*16+15)) for all threads. Kills fastp[3],
//  q0a[3], slow-path bases + branches in the 48-iter inner loop.
//  Affected terms: ~360 of 25.2M get clamped-lerp instead of endpoint clamp
//  (aggregate shift ~1e-5, threshold 2.8e-3).
//   K1: raw -> 16-sample local EMA + inclusive block scan -> B + Eloc.
//   K2: segmented scan -> Y; thread(0,0) zeroes out[0].
//   K3: global long state = Bl + d^(16(tid+1))*Yc -> Etab log2-ratios.
//   K4: replay from B + clamped Etab lerp; block atomicAdd(out).
//  4 dispatches. B layout = v10 scattered [row][sig][col] (proven).
// Fallback (ws < 30.2 MiB): B buffer reused temporally (long then short).

#define T_LEN    1048576
#define CHUNKS   256
#define CLEN     4096
#define NT1      256
#define SEG1     16       // CLEN / NT1; one B column per thread
#define COLS     65536    // T_LEN / 16
#define JMAX     65535
#define EPS_CLIP 1e-8f
#define K2SEG    32
#define K2NSEG   8

struct K1Args {
  float d[6];
  float apw[6][7];        // (d^16)^(2^i), i=0..6  (i=6 -> d^1024)
};
struct K2Args {
  float dL[6];            // d^4096
  float dL32[6];          // d^(4096*32)
};
struct CarryPack {        // one kind (short or long), 3 coefs
  float d[3];
  float apw[3][9];        // (d^16)^(2^i), i=0..8  (i=8 -> d^4096)
};

__device__ __constant__ const int D_SHIFT[3] = {10804, 31972, 63945};

// ---------------- K1: local EMA + inclusive block scan -> B, Eloc ----------
__global__ __launch_bounds__(NT1)
void k1_stage(const float* __restrict__ xp, const float* __restrict__ xt,
              float* __restrict__ Eloc, float* __restrict__ Bs,
              float* __restrict__ Bl, int mode, K1Args ka)
{
  int chunk = blockIdx.x, b = blockIdx.y;       // b = which*4 + sig
  int which = b >> 2, sig = b & 3, tid = threadIdx.x;
  long base = (long)chunk * CLEN + (long)tid * SEG1;
  const float* x0 = (which ? xt : xp) + (long)sig * 2 * T_LEN;
  const float* x1 = x0 + T_LEN;

  float S[12];                                  // j = cf*2 + st
#pragma unroll
  for (int j = 0; j < 12; j++) S[j] = 0.f;

#pragma unroll
  for (int i = 0; i < SEG1 / 4; i++) {
    float4 a = *(const float4*)(x0 + base + 4*i);
    float4 c4 = *(const float4*)(x1 + base + 4*i);
    float sm, sp, pm, ps;
#define STEP(CMP) \
    sm = a.CMP + c4.CMP; sp = a.CMP - c4.CMP; \
    pm = fmaxf(0.5f * sm * sm, EPS_CLIP); ps = fmaxf(0.5f * sp * sp, EPS_CLIP); \
    _Pragma("unroll") \
    for (int cf = 0; cf < 6; cf++) { \
      S[cf*2+0] = fmaf(ka.d[cf], S[cf*2+0], pm); \
      S[cf*2+1] = fmaf(ka.d[cf], S[cf*2+1], ps); \
    }
    STEP(x) STEP(y) STEP(z) STEP(w)
#undef STEP
  }

  // inclusive chunk-local scan across 256 threads (Hillis-Steele + waves)
  int lane = tid & 63, w = tid >> 6;
#pragma unroll
  for (int i = 0; i < 6; i++) {
#pragma unroll
    for (int j = 0; j < 12; j++) {
      float up = __shfl_up(S[j], 1u << i, 64);
      if (lane >= (1 << i)) S[j] = fmaf(ka.apw[j >> 1][i], up, S[j]);
    }
  }
  __shared__ float WT[4][12];
  if (lane == 63)
#pragma unroll
    for (int j = 0; j < 12; j++) WT[w][j] = S[j];
  __syncthreads();
  float C[12];
#pragma unroll
  for (int j = 0; j < 12; j++) C[j] = 0.f;
#pragma unroll
  for (int i = 0; i < 4; i++) {
    if (i < w) {
#pragma unroll
      for (int j = 0; j < 12; j++)
        C[j] = fmaf(ka.apw[j >> 1][6], C[j], WT[i][j]);   // A = d^1024
    }
  }
  float alp[6];                                 // a16^(lane+1)
#pragma unroll
  for (int cf = 0; cf < 6; cf++) {
    int e = lane + 1;
    float a = 1.f;
#pragma unroll
    for (int i = 0; i < 7; i++)
      if (e & (1 << i)) a *= ka.apw[cf][i];
    alp[cf] = a;
  }
#pragma unroll
  for (int j = 0; j < 12; j++) S[j] = fmaf(alp[j >> 1], C[j], S[j]);

  long col = (long)chunk * (CLEN / SEG1) + tid;
  if (mode & 2) {                               // short rows: r = 4k+which*2+st
#pragma unroll
    for (int k = 0; k < 3; k++)
#pragma unroll
      for (int st2 = 0; st2 < 2; st2++)
        Bs[(long)(4*k + which*2 + st2) * (4L*COLS) + (long)sig*COLS + col] = S[4*k + st2];
  }
  if (mode & 1) {                               // long rows
#pragma unroll
    for (int k = 0; k < 3; k++)
#pragma unroll
      for (int st2 = 0; st2 < 2; st2++)
        Bl[(long)(4*k + which*2 + st2) * (4L*COLS) + (long)sig*COLS + col] = S[4*k + 2 + st2];
  }
  if (mode != 2 && tid == NT1 - 1) {            // chunk-end state -> Eloc
#pragma unroll
    for (int cf = 0; cf < 6; cf++)
#pragma unroll
      for (int st = 0; st < 2; st++)
        Eloc[chunk * 96 + (which*8 + sig*2 + st) * 6 + cf] = S[cf*2 + st];
  }
}

// ---------------- K2: segmented scan (96 cols x 8 segments); zero out ------
__global__ __launch_bounds__(768)
void k2_scan(const float* __restrict__ Eloc, float* __restrict__ Y, K2Args ka,
             float* __restrict__ out)
{
  int col = threadIdx.x;        // 0..95
  int seg = threadIdx.y;        // 0..7
  if (col == 0 && seg == 0) out[0] = 0.f;       // zero for k4's atomics
  float dL = ka.dL[col % 6];
  float A  = ka.dL32[col % 6];
  int c0 = seg * K2SEG;

  float yloc[K2SEG];
  float y = 0.f;
#pragma unroll
  for (int i = 0; i < K2SEG; i++) {
    y = fmaf(dL, y, Eloc[(c0 + i) * 96 + col]);
    yloc[i] = y;
  }
  __shared__ float SY[K2NSEG][96];
  SY[seg][col] = y;
  __syncthreads();
  float C = 0.f;
  for (int s = 0; s < seg; s++) C = fmaf(A, C, SY[s][col]);
  float w = dL;
#pragma unroll
  for (int i = 0; i < K2SEG; i++) {
    Y[(c0 + i) * 96 + col] = fmaf(w, C, yloc[i]);
    w *= dL;
  }
}

// ---------------- K3: long table from B (no scan, no raw read) -------------
__global__ __launch_bounds__(256)
void k3_table(const float* __restrict__ Bl, const float* __restrict__ Y,
              float* __restrict__ Etab, CarryPack cp)
{
  int chunk = blockIdx.x, sig = blockIdx.y, tid = threadIdx.x;
  long col = (long)chunk * 256 + tid;

  float Yc[12];
#pragma unroll
  for (int j = 0; j < 12; j++) Yc[j] = 0.f;
  if (chunk > 0) {
    const float* Yp = Y + (chunk - 1) * 96;
    int rm = sig * 2;
#pragma unroll
    for (int k = 0; k < 3; k++) {
      int cf = 2*k + 1;
      Yc[4*k+0] = Yp[rm*6 + cf];       Yc[4*k+1] = Yp[(rm+1)*6 + cf];
      Yc[4*k+2] = Yp[(8+rm)*6 + cf];   Yc[4*k+3] = Yp[(8+rm+1)*6 + cf];
    }
  }
  float fac[3];                                 // a16^(tid+1), tid+1 in [1,256]
#pragma unroll
  for (int k = 0; k < 3; k++) {
    int e = tid + 1;
    float a = 1.f;
#pragma unroll
    for (int i = 0; i < 9; i++)
      if (e & (1 << i)) a *= cp.apw[k][i];
    fac[k] = a;
  }
#pragma unroll
  for (int k = 0; k < 3; k++) {
    float y0 = fmaf(fac[k], Yc[4*k+0], Bl[(long)(4*k+0)*(4L*COLS) + (long)sig*COLS + col]);
    float y1 = fmaf(fac[k], Yc[4*k+1], Bl[(long)(4*k+1)*(4L*COLS) + (long)sig*COLS + col]);
    float y2 = fmaf(fac[k], Yc[4*k+2], Bl[(long)(4*k+2)*(4L*COLS) + (long)sig*COLS + col]);
    float y3 = fmaf(fac[k], Yc[4*k+3], Bl[(long)(4*k+3)*(4L*COLS) + (long)sig*COLS + col]);
    float em = __log2f(y0) - __log2f(y2);       // log2-ratio table
    float es = __log2f(y1) - __log2f(y3);
    long rowm = (long)(k*8 + sig*2);
    Etab[rowm * COLS + col] = em;
    Etab[(rowm+1) * COLS + col] = es;
  }
}

// ---------------- K4: replay from B + CLAMPED table lerp + atomic ----------
__global__ __launch_bounds__(256)
void k4all(const float* __restrict__ xp, const float* __restrict__ xt,
           const float* __restrict__ Y, const float* __restrict__ Bs,
           const float* __restrict__ Etab, CarryPack cp, float* __restrict__ out)
{
  int chunk = blockIdx.x, sig = blockIdx.y, tid = threadIdx.x;
  long col = (long)chunk * 256 + tid;
  long base = col * 16;

  // carry-in: global short-EMA states at sample base-1
  float Yc[12];
#pragma unroll
  for (int j = 0; j < 12; j++) Yc[j] = 0.f;
  if (chunk > 0) {
    const float* Yp = Y + (chunk - 1) * 96;
    int rm = sig * 2;
#pragma unroll
    for (int k = 0; k < 3; k++) {
      int cf = 2*k;
      Yc[4*k+0] = Yp[rm*6 + cf];       Yc[4*k+1] = Yp[(rm+1)*6 + cf];
      Yc[4*k+2] = Yp[(8+rm)*6 + cf];   Yc[4*k+3] = Yp[(8+rm+1)*6 + cf];
    }
  }
  float y[12];
  if (tid == 0) {
#pragma unroll
    for (int j = 0; j < 12; j++) y[j] = Yc[j];  // Y[chunk-1] is exact carry
  } else {
    float fac[3];                               // a16^tid, tid in [1,256)
#pragma unroll
    for (int k = 0; k < 3; k++) {
      float a = 1.f;
#pragma unroll
      for (int i = 0; i < 8; i++)
        if (tid & (1 << i)) a *= cp.apw[k][i];
      fac[k] = a;
    }
#pragma unroll
    for (int k = 0; k < 3; k++)
#pragma unroll
      for (int q = 0; q < 4; q++)
        y[4*k+q] = fmaf(fac[k], Yc[4*k+q],
                        Bs[(long)(4*k+q)*(4L*COLS) + (long)sig*COLS + (col-1)]);
  }

  // table fetches: single CLAMPED lerp path (no slow path, no branches).
  // qc = clamp(q0-15, 0, (JMAX-2)*16+15); affects ~360/25.2M terms by ~1e-5.
  float tm0[3], tm1[3], tm2[3], ts0[3], ts1[3], ts2[3];
  int ofs[3];
#pragma unroll
  for (int k = 0; k < 3; k++) {
    int q0 = (int)base + D_SHIFT[k]; if (q0 >= T_LEN) q0 -= T_LEN;
    int qc = q0 - 15;
    qc = qc < 0 ? 0 : qc;
    const int QCAP = ((JMAX - 2) << 4) + 15;
    qc = qc > QCAP ? QCAP : qc;
    int j0 = qc >> 4;
    ofs[k] = qc & 15;
    const float* Tm = Etab + (long)(k * 8 + sig * 2) * COLS;
    const float* Ts = Tm + COLS;
    tm0[k] = Tm[j0]; tm1[k] = Tm[j0 + 1]; tm2[k] = Tm[j0 + 2];
    ts0[k] = Ts[j0]; ts1[k] = Ts[j0 + 1]; ts2[k] = Ts[j0 + 2];
  }

  const float* p0 = xp + (long)sig * 2 * T_LEN;
  const float* p1 = p0 + T_LEN;
  const float* t0 = xt + (long)sig * 2 * T_LEN;
  const float* t1 = t0 + T_LEN;

  float acc0 = 0.f, acc1 = 0.f;
#pragma unroll
  for (int qt = 0; qt < 4; qt++) {
    float4 a4 = *(const float4*)(p0 + base + 4*qt);
    float4 b4 = *(const float4*)(p1 + base + 4*qt);
    float4 u4 = *(const float4*)(t0 + base + 4*qt);
    float4 w4 = *(const float4*)(t1 + base + 4*qt);
#define SAMP(CI, CMP) { \
      const int m = 4*qt + CI; \
      float sm = a4.CMP + b4.CMP, sd = a4.CMP - b4.CMP; \
      float pm = fmaxf(0.5f*sm*sm, EPS_CLIP), ps = fmaxf(0.5f*sd*sd, EPS_CLIP); \
      float em_ = u4.CMP + w4.CMP, ed_ = u4.CMP - w4.CMP; \
      float qm_ = fmaxf(0.5f*em_*em_, EPS_CLIP), qs_ = fmaxf(0.5f*ed_*ed_, EPS_CLIP); \
      _Pragma("unroll") \
      for (int k = 0; k < 3; k++) { \
        float dd = cp.d[k]; \
        y[4*k+0] = fmaf(dd, y[4*k+0], pm);  y[4*k+1] = fmaf(dd, y[4*k+1], ps); \
        y[4*k+2] = fmaf(dd, y[4*k+2], qm_); y[4*k+3] = fmaf(dd, y[4*k+3], qs_); \
        float Dm = __log2f(y[4*k+0]) - __log2f(y[4*k+2]); \
        float Ds = __log2f(y[4*k+1]) - __log2f(y[4*k+3]); \
        int d0 = ofs[k] + m; \
        bool hi = d0 >= 16; \
        float am = hi ? tm1[k] : tm0[k], bm = hi ? tm2[k] : tm1[k]; \
        float as = hi ? ts1[k] : ts0[k], bs = hi ? ts2[k] : ts1[k]; \
        float f = (float)(d0 - (hi ? 16 : 0)) * 0.0625f; \
        float em = fmaf(f, bm - am, am); \
        float es = fmaf(f, bs - as, as); \
        acc0 += fabsf(Dm - em); \
        acc1 += fabsf(Ds - es); \
      } \
    }
    SAMP(0,x) SAMP(1,y) SAMP(2,z) SAMP(3,w)
#undef SAMP
  }

  float acc = acc0 + acc1;
#pragma unroll
  for (int off = 32; off > 0; off >>= 1) acc += __shfl_down(acc, off, 64);
  __shared__ float psum[4];
  int lane = tid & 63, w = tid >> 6;
  if (lane == 0) psum[w] = acc;
  __syncthreads();
  if (tid == 0) {
    const float SCALE = (float)(0.6931471805599453 / (8.0 * 1048576.0));
    float s = psum[0] + psum[1] + psum[2] + psum[3];
    atomicAdd(out, s * SCALE);                  // device-scope; absorbs k5
  }
}

extern "C" void kernel_launch(void* const* d_in, const int* in_sizes, int n_in,
                              void* d_out, int out_size, void* d_ws, size_t ws_size,
                              hipStream_t stream)
{
  (void)in_sizes; (void)n_in; (void)out_size;
  const float* xp = (const float*)d_in[0];
  const float* xt = (const float*)d_in[1];
  float* out = (float*)d_out;
  char* ws = (char*)d_ws;

  const size_t OFF_ELOC = 0;          // 256*96*4 = 98304
  const size_t OFF_Y    = 98304;      // 98304
  const size_t OFF_ETAB = 212992;     // 24*65536*4 = 6 MB, ends 6504448
  const size_t OFF_B    = 6504448;    // 12 rows = 12.6 MB; 24 rows = 25.2 MB
  const size_t HALF_B   = 12L * 4 * COLS * 4;          // 12582912
  const size_t NEED_FULL = OFF_B + 2 * HALF_B;         // 31670272 (~30.2 MiB)
  float* Eloc = (float*)(ws + OFF_ELOC);
  float* Ybuf = (float*)(ws + OFF_Y);
  float* Etab = (float*)(ws + OFF_ETAB);
  float* Bsh  = (float*)(ws + OFF_B);                  // short rows
  float* Blo  = (float*)(ws + OFF_B + HALF_B);         // long rows (full mode)

  static const double S_MS[3] = {10.0, 50.0, 100.0};
  static const double L_MS[3] = {500.0, 1500.0, 3000.0};

  K1Args k1a; K2Args k2a; CarryPack cpS, cpL;
  for (int k = 0; k < 3; k++) {
    for (int which = 0; which < 2; which++) {
      int idx = 2 * k + which;
      double ms = which ? L_MS[k] : S_MS[k];
      float cF = (float)(1.0 - std::exp(-2200.0 / (ms * 44100.0)));
      float dF = 1.0f - cF;               // exact fp32 match to reference
      k1a.d[idx] = dF;
      double a16 = std::pow((double)dF, 16.0);
      for (int i = 0; i < 7; i++)
        k1a.apw[idx][i] = (float)std::pow(a16, (double)(1 << i));
      k2a.dL[idx]   = (float)std::pow((double)dF, (double)CLEN);
      k2a.dL32[idx] = (float)std::pow((double)dF, (double)CLEN * (double)K2SEG);
      CarryPack& cp = which ? cpL : cpS;
      cp.d[k] = dF;
      for (int i = 0; i < 9; i++)
        cp.apw[k][i] = (float)std::pow(a16, (double)(1 << i));
    }
  }

  bool full = (ws_size >= NEED_FULL);
  if (full) {
    k1_stage<<<dim3(CHUNKS, 8), NT1, 0, stream>>>(xp, xt, Eloc, Bsh, Blo, 3, k1a);
    k2_scan<<<dim3(1), dim3(96, K2NSEG), 0, stream>>>(Eloc, Ybuf, k2a, out);
    k3_table<<<dim3(CHUNKS, 4), 256, 0, stream>>>(Blo, Ybuf, Etab, cpL);
    k4all<<<dim3(CHUNKS, 4), 256, 0, stream>>>(xp, xt, Ybuf, Bsh, Etab, cpS, out);
  } else {
    // 19.1 MB budget: reuse the single 12-row B buffer temporally
    k1_stage<<<dim3(CHUNKS, 8), NT1, 0, stream>>>(xp, xt, Eloc, Bsh, Bsh, 1, k1a);
    k2_scan<<<dim3(1), dim3(96, K2NSEG), 0, stream>>>(Eloc, Ybuf, k2a, out);
    k3_table<<<dim3(CHUNKS, 4), 256, 0, stream>>>(Bsh, Ybuf, Etab, cpL);
    k1_stage<<<dim3(CHUNKS, 8), NT1, 0, stream>>>(xp, xt, Eloc, Bsh, Bsh, 2, k1a);
    k4all<<<dim3(CHUNKS, 4), 256, 0, stream>>>(xp, xt, Ybuf, Bsh, Etab, cpS, out);
  }
}